// Round 7
// baseline (260.913 us; speedup 1.0000x reference)
//
#include <hip/hip_runtime.h>
#include <hip/hip_bf16.h>
#include <hip/hip_fp16.h>
#include <math.h>

#define B_ 8
#define Q_ 150
#define QP_ 160     // padded Q for MFMA (10 m-tiles of 16)
#define C_ 134
#define T_ 32
#define H_ 160
#define W_ 160
#define P_ 12544
#define HW_ (H_ * W_)
#define HW4_ (HW_ / 4)

#define XTOT (Q_ + T_)        // 182 images per batch slot
#define SBLK 512              // sampler block size
#define NBAT 6                // 6 batches x 4 points x 512 thr = 12288
#define TAILP 128             // tail pairs, handled by tid < 128
// GEMM
#define SEG_ 56
#define KSEG 224              // P_/SEG_
#define KITER 7               // KSEG/32
#define DSTRIDE (2 * B_ * QP_ * T_)   // 81920 floats per segment slab

typedef __attribute__((ext_vector_type(8))) short short8;
typedef __attribute__((ext_vector_type(4))) float floatx4;
typedef __attribute__((ext_vector_type(2))) _Float16 half2v;
typedef __attribute__((ext_vector_type(2))) __fp16 fp16x2;
typedef unsigned uua __attribute__((aligned(2)));   // for unaligned ds_read_b32

__device__ __forceinline__ float waveSum(float v) {
#pragma unroll
  for (int m = 32; m >= 1; m >>= 1) v += __shfl_xor(v, m, 64);
  return v;
}
__device__ __forceinline__ float waveMax(float v) {
#pragma unroll
  for (int m = 32; m >= 1; m >>= 1) v = fmaxf(v, __shfl_xor(v, m, 64));
  return v;
}

__device__ __forceinline__ unsigned short f2bf(float x) {
  union { __hip_bfloat16 h; unsigned short u; } cv;
  cv.h = __float2bfloat16(x);
  return cv.u;
}
__device__ __forceinline__ float bf2f(unsigned short u) {
  return __uint_as_float(((unsigned int)u) << 16);
}
__device__ __forceinline__ unsigned short f2h(float x) {
  union { __half h; unsigned short u; } cv;
  cv.h = __float2half(x);
  return cv.u;
}
// packed f32x2 -> f16x2 (one v_cvt_pkrtz_f16_f32); bit-cast via __fp16 union
__device__ __forceinline__ unsigned pk_f16(float a, float b) {
  union { fp16x2 h; unsigned u; } cv;
  cv.h = __builtin_amdgcn_cvt_pkrtz(a, b);
  return cv.u;
}

// ---------------- phase 0: precompute packed bilinear coeffs per (b,p).
// One uint4 per point:
//   x = byte offset of the (v00,v01) pair in the f16 image [bits 0..15]
//       | row step bytes [bits 17+] (320 if y1 row valid, else 0; premult)
//   y = half2(w00, w01), z = half2(w10, w11), w = unused
// Base pixel remapped so it is always in-bounds; out-of-image taps carry
// zero weight. The pair-read may touch the 2 zeroed pad halfwords past the
// image end (finite, so 0-weight kills them).
__launch_bounds__(256) __global__
void samp_kernel(const float* __restrict__ coords,
                 uint4* __restrict__ sPack) {
  int i = blockIdx.x * 256 + threadIdx.x;  // over B_*P_
  float2 cc = ((const float2*)coords)[i];
  float x = cc.x * (float)W_ - 0.5f;
  float y = cc.y * (float)H_ - 0.5f;
  float x0f = floorf(x), y0f = floorf(y);
  float tx = x - x0f, ty = y - y0f;
  int x0 = (int)x0f, y0 = (int)y0f;

  bool vx0 = (x0 >= 0) && (x0 < W_);
  bool vx1 = (x0 + 1 >= 0) && (x0 + 1 < W_);
  int bx; float wx0, wx1;
  if (vx0) { bx = x0; wx0 = 1.f - tx; wx1 = vx1 ? tx : 0.f; }
  else     { bx = min(max(x0 + 1, 0), W_ - 1); wx0 = vx1 ? tx : 0.f; wx1 = 0.f; }

  bool vy0 = (y0 >= 0) && (y0 < H_);
  bool vy1 = (y0 + 1 >= 0) && (y0 + 1 < H_);
  int by, ir; float wy0, wy1;
  if (vy0) {
    by = y0; wy0 = 1.f - ty;
    if (vy1) { wy1 = ty; ir = 1; } else { wy1 = 0.f; ir = 0; }
  } else {
    by = min(max(y0 + 1, 0), H_ - 1); wy0 = vy1 ? ty : 0.f; wy1 = 0.f; ir = 0;
  }

  int pi = by * W_ + bx;
  uint4 u;
  u.x = (unsigned)(2 * pi) | (ir ? (320u << 17) : 0u);
  u.y = (unsigned)f2h(wx0 * wy0) | ((unsigned)f2h(wx1 * wy0) << 16);
  u.z = (unsigned)f2h(wx0 * wy1) | ((unsigned)f2h(wx1 * wy1) << 16);
  u.w = 0u;
  sPack[i] = u;
}

// 2-read bilinear tap from single f16 image: unaligned ds_read_b32 fetches
// each horizontally-adjacent pixel pair in one op; packed f16 FMA does the
// 4-tap dot in 2 pk ops + 2 cvt + 1 add.
__device__ __forceinline__ float lds2(const unsigned short* im, uint4 pk) {
  const char* base = (const char*)im;
  unsigned o00 = pk.x & 0xffffu;
  unsigned o10 = o00 + (pk.x >> 17);   // +0 or +320 bytes (one image row)
  unsigned p0 = *(const uua*)(base + o00);
  unsigned p1 = *(const uua*)(base + o10);
  union { unsigned u; half2v h; } a, b, wy, wz;
  a.u = p0; b.u = p1; wy.u = pk.y; wz.u = pk.z;
  half2v prod = a.h * wy.h + b.h * wz.h;   // v_pk_mul/fma_f16
  return (float)prod.x + (float)prod.y;
}

// load one batch (2 chunks = 4 points: pairs at chunk 2*bat, 2*bat+1)
#define LOADPK(dst, bat_)                        \
  do {                                           \
    int p0_ = (bat_) * 2048 + 2 * tid;           \
    dst[0] = sp[p0_];                            \
    dst[1] = sp[p0_ + 1];                        \
    dst[2] = sp[p0_ + 1024];                     \
    dst[3] = sp[p0_ + 1025];                     \
  } while (0)

// ---------------- phase 1+2 fused: sample pm (x<Q_) or tm (x>=Q_).
// f16 image (51.2KB + 4B pad), 512-thr blocks, register-db sPack prefetch.
__launch_bounds__(SBLK, 6) __global__
void sample_kernel(const float* __restrict__ masks_q,
                   const float* __restrict__ mask_labels,
                   const uint4* __restrict__ sPack,
                   unsigned short* __restrict__ pmh,
                   unsigned short* __restrict__ tmh,
                   float* __restrict__ S_sp, float* __restrict__ S_sig,
                   float* __restrict__ S_tm) {
  __shared__ unsigned short img[HW_ + 2];   // f16 pixels + 2 zero pad
  __shared__ float red[32];
  const int x = blockIdx.x;
  const int b = blockIdx.y;
  const int tid = threadIdx.x;
  const bool isPm = (x < Q_);

  const uint4* sp = sPack + (size_t)b * P_;

  // batch-0 pk loads: issued before staging, hide under the HBM loads
  uint4 pk[2][4];
  LOADPK(pk[0], 0);

  const float* src = isPm ? (masks_q + ((size_t)b * Q_ + x) * HW_)
                          : (mask_labels + ((size_t)b * T_ + (x - Q_)) * HW_);
  const float4* s4 = (const float4*)src;
#pragma unroll
  for (int c = 0; c < 12; ++c) {
    int i = c * SBLK + tid;
    float4 v = s4[i];
    uint2 u;
    u.x = pk_f16(v.x, v.y);
    u.y = pk_f16(v.z, v.w);
    *(uint2*)&img[4 * i] = u;
  }
  if (tid < HW4_ - 12 * SBLK) {  // 6400 - 6144 = 256
    int i = 12 * SBLK + tid;
    float4 v = s4[i];
    uint2 u;
    u.x = pk_f16(v.x, v.y);
    u.y = pk_f16(v.z, v.w);
    *(uint2*)&img[4 * i] = u;
  }
  if (tid == 0) *(unsigned*)&img[HW_] = 0u;   // zero the pad pair
  __syncthreads();

  uint4 ta, tb;   // tail pair, prefetched during batch 4

  if (isPm) {
    unsigned short* dst = pmh + ((size_t)b * QP_ + x) * P_;
    unsigned* dst32 = (unsigned*)dst;
    float ssp = 0.f, ssg = 0.f;
#pragma unroll
    for (int bat = 0; bat < NBAT; ++bat) {
      if (bat < NBAT - 1) LOADPK(pk[(bat + 1) & 1], bat + 1);
      if (bat == NBAT - 2 && tid < TAILP) {
        ta = sp[12288 + 2 * tid];
        tb = sp[12288 + 2 * tid + 1];
      }
      const uint4* cur = pk[bat & 1];
      float v[4];
#pragma unroll
      for (int j = 0; j < 4; ++j) v[j] = lds2(img, cur[j]);
#pragma unroll
      for (int cc = 0; cc < 2; ++cc) {
        unsigned pr = 0;
#pragma unroll
        for (int k = 0; k < 2; ++k) {
          float pm = v[2 * cc + k];
          float e = __expf(-fabsf(pm));
          float r = __builtin_amdgcn_rcpf(1.f + e);
          float sp_ = fmaxf(pm, 0.f) - __logf(r);
          float sg = (pm >= 0.f) ? r : e * r;
          ssp += sp_;
          ssg += sg;
          pr |= ((unsigned)f2bf(pm)) << (16 * k);
        }
        dst32[(2 * bat + cc) * SBLK + tid] = pr;
      }
    }
    if (tid < TAILP) {
      float v0 = lds2(img, ta), v1 = lds2(img, tb);
      unsigned pr = 0;
#pragma unroll
      for (int k = 0; k < 2; ++k) {
        float pm = (k == 0) ? v0 : v1;
        float e = __expf(-fabsf(pm));
        float r = __builtin_amdgcn_rcpf(1.f + e);
        float sp_ = fmaxf(pm, 0.f) - __logf(r);
        float sg = (pm >= 0.f) ? r : e * r;
        ssp += sp_;
        ssg += sg;
        pr |= ((unsigned)f2bf(pm)) << (16 * k);
      }
      dst32[6144 + tid] = pr;
    }
    ssp = waveSum(ssp);
    ssg = waveSum(ssg);
    int w = tid >> 6;
    if ((tid & 63) == 0) {
      red[w] = ssp;
      red[16 + w] = ssg;
    }
    __syncthreads();
    if (tid == 0) {
      float a = 0.f, bb = 0.f;
#pragma unroll
      for (int i = 0; i < 8; ++i) { a += red[i]; bb += red[16 + i]; }
      S_sp[b * Q_ + x] = a;
      S_sig[b * Q_ + x] = bb;
    }
  } else {
    const int t = x - Q_;
    unsigned short* dst = tmh + ((size_t)b * T_ + t) * P_;
    unsigned* dst32 = (unsigned*)dst;
    float stm = 0.f;
#pragma unroll
    for (int bat = 0; bat < NBAT; ++bat) {
      if (bat < NBAT - 1) LOADPK(pk[(bat + 1) & 1], bat + 1);
      if (bat == NBAT - 2 && tid < TAILP) {
        ta = sp[12288 + 2 * tid];
        tb = sp[12288 + 2 * tid + 1];
      }
      const uint4* cur = pk[bat & 1];
      float v[4];
#pragma unroll
      for (int j = 0; j < 4; ++j) v[j] = lds2(img, cur[j]);
#pragma unroll
      for (int cc = 0; cc < 2; ++cc) {
        float v0 = v[2 * cc], v1 = v[2 * cc + 1];
        stm += v0 + v1;
        unsigned pr = (unsigned)f2bf(v0) | (((unsigned)f2bf(v1)) << 16);
        dst32[(2 * bat + cc) * SBLK + tid] = pr;
      }
    }
    if (tid < TAILP) {
      float v0 = lds2(img, ta), v1 = lds2(img, tb);
      stm += v0 + v1;
      unsigned pr = (unsigned)f2bf(v0) | (((unsigned)f2bf(v1)) << 16);
      dst32[6144 + tid] = pr;
    }
    stm = waveSum(stm);
    int w = tid >> 6;
    if ((tid & 63) == 0) red[w] = stm;
    __syncthreads();
    if (tid == 0) {
      float a = 0.f;
#pragma unroll
      for (int i = 0; i < 8; ++i) a += red[i];
      S_tm[b * T_ + t] = a;
    }
  }
}

// convert a pm bf16 A-frag to a sigmoid(pm) bf16 A-frag, elementwise
__device__ __forceinline__ short8 sig_frag(short8 a) {
  short8 out;
#pragma unroll
  for (int j = 0; j < 8; ++j) {
    float x = bf2f((unsigned short)a[j]);
    float e = __expf(-fabsf(x));
    float r = __builtin_amdgcn_rcpf(1.f + e);
    float sg = (x >= 0.f) ? r : e * r;
    out[j] = (short)f2bf(sg);
  }
  return out;
}

// ---------------- phase 3: K-split MFMA GEMM, atomic-free partials.
__launch_bounds__(320) __global__
void gemm_kernel(const unsigned short* __restrict__ pmh,
                 const unsigned short* __restrict__ tmh,
                 float* __restrict__ accP) {
  const int b = blockIdx.y;
  const int seg = blockIdx.x;
  const int w = threadIdx.x >> 6;
  const int l = threadIdx.x & 63;
  const int quad = l >> 4;
  const int mrow = l & 15;

  const unsigned short* pmb = pmh + ((size_t)b * QP_ + w * 32) * P_;
  const unsigned short* tmb = tmh + (size_t)b * T_ * P_;

  floatx4 aL[2][2];  // [m-tile local][n-tile]
  floatx4 aS[2][2];
#pragma unroll
  for (int i = 0; i < 2; ++i)
#pragma unroll
    for (int j = 0; j < 2; ++j) {
      aL[i][j] = (floatx4){0.f, 0.f, 0.f, 0.f};
      aS[i][j] = (floatx4){0.f, 0.f, 0.f, 0.f};
    }

  const int kbase = seg * KSEG;
#pragma unroll
  for (int ki = 0; ki < KITER; ++ki) {
    const int k0 = kbase + ki * 32 + quad * 8;
    short8 a0 = *(const short8*)(pmb + (size_t)(0 * 16 + mrow) * P_ + k0);
    short8 a1 = *(const short8*)(pmb + (size_t)(1 * 16 + mrow) * P_ + k0);
    short8 b0 = *(const short8*)(tmb + (size_t)(0 * 16 + mrow) * P_ + k0);
    short8 b1 = *(const short8*)(tmb + (size_t)(1 * 16 + mrow) * P_ + k0);
    short8 s0 = sig_frag(a0);
    short8 s1 = sig_frag(a1);
    aL[0][0] = __builtin_amdgcn_mfma_f32_16x16x32_bf16(a0, b0, aL[0][0], 0, 0, 0);
    aL[0][1] = __builtin_amdgcn_mfma_f32_16x16x32_bf16(a0, b1, aL[0][1], 0, 0, 0);
    aL[1][0] = __builtin_amdgcn_mfma_f32_16x16x32_bf16(a1, b0, aL[1][0], 0, 0, 0);
    aL[1][1] = __builtin_amdgcn_mfma_f32_16x16x32_bf16(a1, b1, aL[1][1], 0, 0, 0);
    aS[0][0] = __builtin_amdgcn_mfma_f32_16x16x32_bf16(s0, b0, aS[0][0], 0, 0, 0);
    aS[0][1] = __builtin_amdgcn_mfma_f32_16x16x32_bf16(s0, b1, aS[0][1], 0, 0, 0);
    aS[1][0] = __builtin_amdgcn_mfma_f32_16x16x32_bf16(s1, b0, aS[1][0], 0, 0, 0);
    aS[1][1] = __builtin_amdgcn_mfma_f32_16x16x32_bf16(s1, b1, aS[1][1], 0, 0, 0);
  }

  // epilogue: plain stores. D layout: row(m)=quad*4+reg, col(n)=lane&15
  float* base = accP + (size_t)seg * DSTRIDE;
#pragma unroll
  for (int mtl = 0; mtl < 2; ++mtl)
#pragma unroll
    for (int nt = 0; nt < 2; ++nt)
#pragma unroll
      for (int r = 0; r < 4; ++r) {
        int q = w * 32 + mtl * 16 + quad * 4 + r;
        int t = nt * 16 + mrow;
        base[((size_t)(0 * B_ + b) * QP_ + q) * T_ + t] = aL[mtl][nt][r];
        base[((size_t)(1 * B_ + b) * QP_ + q) * T_ + t] = aS[mtl][nt][r];
      }
}

// ---------------- phase 4: finalize (reduce fused). one wave per (b,q).
__launch_bounds__(64) __global__
void final_kernel(const float* __restrict__ class_q,
                  const int* __restrict__ labels,
                  const float* __restrict__ accP,
                  const float* __restrict__ S_sp,
                  const float* __restrict__ S_sig,
                  const float* __restrict__ S_tm,
                  float* __restrict__ out) {
  const int bq = blockIdx.x;
  const int b = bq / Q_;
  const int q = bq % Q_;
  const int l = threadIdx.x;
  const float* cl = class_q + (size_t)bq * C_;

  // segment reduction: lane l -> matrix (l>>5), column (l&31)
  const int mat = l >> 5;
  const int t = l & 31;
  const float* ap = accP + ((size_t)(mat * B_ + b) * QP_ + q) * T_ + t;
  float s = 0.f;
#pragma unroll
  for (int seg = 0; seg < SEG_; ++seg) s += ap[(size_t)seg * DSTRIDE];
  float sOther = __shfl_xor(s, 32, 64);   // lane<32: Dsig from lane+32

  float v = -INFINITY;
  for (int c = l; c < C_; c += 64) v = fmaxf(v, cl[c]);
  float m = waveMax(v);
  float e = 0.f;
  for (int c = l; c < C_; c += 64) e += __expf(cl[c] - m);
  float den = waveSum(e);

  if (l < T_) {
    int lbl = labels[b * T_ + t];
    float prob = __expf(cl[lbl] - m) / den;
    float Dlin = s;
    float Dsig = sOther;
    float cmask = (S_sp[bq] - Dlin) * (1.f / (float)P_);
    float dice = 1.f - (2.f * Dsig + 1.f) / (S_sig[bq] + S_tm[b * T_ + t] + 1.f);
    out[(size_t)bq * T_ + t] = 5.f * cmask + 5.f * dice - prob;
  }
}

extern "C" void kernel_launch(void* const* d_in, const int* in_sizes, int n_in,
                              void* d_out, int out_size, void* d_ws,
                              size_t ws_size, hipStream_t stream) {
  const float* masks_q = (const float*)d_in[0];      // [B,Q,H,W]
  const float* class_q = (const float*)d_in[1];      // [B,Q,C]
  const float* mask_labels = (const float*)d_in[2];  // [B,T,H,W]
  const int* class_labels = (const int*)d_in[3];     // [B,T]
  const float* coords = (const float*)d_in[4];       // [B,P,2]
  float* out = (float*)d_out;

  // ws layout (accD slot retained for layout stability; unused now)
  float* accD = (float*)d_ws;                         // [2][B][QP_][T_] (unused)
  float* accP = accD + DSTRIDE;                       // [SEG_][2][B][QP_][T_]
  uint4* sPack = (uint4*)(accP + (size_t)SEG_ * DSTRIDE);  // [B*P] (16B aligned)
  float* S_sp = (float*)(sPack + (size_t)B_ * P_);    // [B*Q]
  float* S_sig = S_sp + B_ * Q_;                      // [B*Q]
  float* S_tm = S_sig + B_ * Q_;                      // [B*T]
  unsigned short* pmh = (unsigned short*)(S_tm + B_ * T_);  // [B][QP_][P]
  unsigned short* tmh = pmh + (size_t)B_ * QP_ * P_;        // [B][T][P]

  samp_kernel<<<(B_ * P_) / 256, 256, 0, stream>>>(coords, sPack);
  sample_kernel<<<dim3(XTOT, B_), SBLK, 0, stream>>>(
      masks_q, mask_labels, sPack, pmh, tmh, S_sp, S_sig, S_tm);
  gemm_kernel<<<dim3(SEG_, B_), 320, 0, stream>>>(pmh, tmh, accP);
  final_kernel<<<B_ * Q_, 64, 0, stream>>>(class_q, class_labels, accP, S_sp,
                                           S_sig, S_tm, out);
}

// Round 10
// 237.493 us; speedup vs baseline: 1.0986x; 1.0986x over previous
//
#include <hip/hip_runtime.h>
#include <hip/hip_bf16.h>
#include <hip/hip_fp16.h>
#include <math.h>

#define B_ 8
#define Q_ 150
#define QP_ 160     // padded Q for MFMA (10 m-tiles of 16)
#define C_ 134
#define T_ 32
#define H_ 160
#define W_ 160
#define P_ 12544
#define HW_ (H_ * W_)
#define HW4_ (HW_ / 4)

#define SBLK 1024           // sampler block size
// 12544 points = 6 chunks of 2048 (pairs: 2*tid) + tail of 256 (128 pairs)
#define NCHUNK 6
#define TAILP 128           // tail pairs, handled by tid < 128
// GEMM
#define SEG_ 56
#define KSEG 224            // P_/SEG_
#define KITER 7             // KSEG/32
#define DSTRIDE (2 * B_ * QP_ * T_)   // 81920 floats per segment slab

typedef __attribute__((ext_vector_type(8))) short short8;
typedef __attribute__((ext_vector_type(4))) float floatx4;

__device__ __forceinline__ float waveSum(float v) {
#pragma unroll
  for (int m = 32; m >= 1; m >>= 1) v += __shfl_xor(v, m, 64);
  return v;
}
__device__ __forceinline__ float waveMax(float v) {
#pragma unroll
  for (int m = 32; m >= 1; m >>= 1) v = fmaxf(v, __shfl_xor(v, m, 64));
  return v;
}

__device__ __forceinline__ unsigned short f2bf(float x) {
  union { __hip_bfloat16 h; unsigned short u; } cv;
  cv.h = __float2bfloat16(x);
  return cv.u;
}
__device__ __forceinline__ float bf2f(unsigned short u) {
  return __uint_as_float(((unsigned int)u) << 16);
}
__device__ __forceinline__ float h2f(unsigned u) {
  union { __half h; unsigned short u; } cv;
  cv.u = (unsigned short)u;
  return __half2float(cv.h);
}
__device__ __forceinline__ unsigned short f2h(float x) {
  union { __half h; unsigned short u; } cv;
  cv.h = __float2half(x);
  return cv.u;
}

// ---------------- phase 0: precompute packed bilinear coeffs per (b,p).
// One uint4 per point:
//   x = byte offset of tap00 in bf16 image [bits 0..15]
//       | dx flag        [bit 16]  (tap01 = tap00 + 2 bytes if set)
//       | row step bytes [bits 17+] (320 if y1 row valid, else 0; premult)
//   y = half2(w00, w01), z = half2(w10, w11), w = unused
// Base pixel is remapped so it is always in-bounds; out-of-image taps get
// zero weight (their reads land inside the shared block and are harmless).
__launch_bounds__(256) __global__
void samp_kernel(const float* __restrict__ coords,
                 uint4* __restrict__ sPack) {
  int i = blockIdx.x * 256 + threadIdx.x;  // over B_*P_
  float2 cc = ((const float2*)coords)[i];
  float x = cc.x * (float)W_ - 0.5f;
  float y = cc.y * (float)H_ - 0.5f;
  float x0f = floorf(x), y0f = floorf(y);
  float tx = x - x0f, ty = y - y0f;
  int x0 = (int)x0f, y0 = (int)y0f;

  bool vx0 = (x0 >= 0) && (x0 < W_);
  bool vx1 = (x0 + 1 >= 0) && (x0 + 1 < W_);
  int bx; float wx0, wx1;
  if (vx0) { bx = x0; wx0 = 1.f - tx; wx1 = vx1 ? tx : 0.f; }
  else     { bx = min(max(x0 + 1, 0), W_ - 1); wx0 = vx1 ? tx : 0.f; wx1 = 0.f; }

  bool vy0 = (y0 >= 0) && (y0 < H_);
  bool vy1 = (y0 + 1 >= 0) && (y0 + 1 < H_);
  int by, ir; float wy0, wy1;
  if (vy0) {
    by = y0; wy0 = 1.f - ty;
    if (vy1) { wy1 = ty; ir = 1; } else { wy1 = 0.f; ir = 0; }
  } else {
    by = min(max(y0 + 1, 0), H_ - 1); wy0 = vy1 ? ty : 0.f; wy1 = 0.f; ir = 0;
  }

  int pi = by * W_ + bx;
  unsigned dxbit = (bx + 1 < W_) ? (1u << 16) : 0u;
  unsigned dyf = ir ? (320u << 17) : 0u;
  uint4 u;
  u.x = (unsigned)(2 * pi) | dxbit | dyf;
  u.y = (unsigned)f2h(wx0 * wy0) | ((unsigned)f2h(wx1 * wy0) << 16);
  u.z = (unsigned)f2h(wx0 * wy1) | ((unsigned)f2h(wx1 * wy1) << 16);
  u.w = 0u;
  sPack[i] = u;
}

// 4-tap bilinear gather from single bf16 image copy. 3 ALU ops to derive
// all 4 byte addresses, 4 independent ds_read_u16.
__device__ __forceinline__ float lds4(const unsigned short* img, uint4 pk) {
  const char* base = (const char*)img;
  unsigned o00 = pk.x & 0xffffu;
  unsigned dx2 = (pk.x >> 15) & 2u;          // 0 or 2 bytes
  unsigned o10 = o00 + (pk.x >> 17);         // +0 or +320 bytes
  unsigned short v00 = *(const unsigned short*)(base + o00);
  unsigned short v01 = *(const unsigned short*)(base + o00 + dx2);
  unsigned short v10 = *(const unsigned short*)(base + o10);
  unsigned short v11 = *(const unsigned short*)(base + o10 + dx2);
  return h2f(pk.y & 0xffffu) * bf2f(v00) + h2f(pk.y >> 16) * bf2f(v01) +
         h2f(pk.z & 0xffffu) * bf2f(v10) + h2f(pk.z >> 16) * bf2f(v11);
}

// ---------------- phase 1+2 fused: sample pm (x<Q_) or tm (x>=Q_)
// Single bf16 image copy (51.2 KB -> 2 blocks/CU). Each thread owns
// adjacent point PAIRS: one uint4 pk load per point, paired dword stores,
// 6-point ILP batches (24 ds_read_u16 in flight).
// Session note (R0-R9): this phase is pinned at ~72 us with ALL pipes
// <=31% (VALU/LDS/HBM). Occupancy 39-75%, ILP 4-12, HBM/sPack prefetch
// (C-level and inline-asm counted-vmcnt), f16 image + packed math, and
// bank-conflict elimination (5.7M->0 via unaligned b32) all failed to
// move it. The stall source is not identifiable from SQ/TCC counters;
// progress requires disasm/stall-reason evidence.
__launch_bounds__(SBLK, 8) __global__
void sample_kernel(const float* __restrict__ masks_q,
                   const float* __restrict__ mask_labels,
                   const uint4* __restrict__ sPack,
                   unsigned short* __restrict__ pmh,
                   unsigned short* __restrict__ tmh,
                   float* __restrict__ S_sp, float* __restrict__ S_sig,
                   float* __restrict__ S_tm) {
  __shared__ unsigned short img[HW_];   // 51200 B
  __shared__ float red[32];
  const int x = blockIdx.x;
  const int b = blockIdx.y;
  const int tid = threadIdx.x;
  const bool isPm = (x < Q_);

  const float* src = isPm ? (masks_q + ((size_t)b * Q_ + x) * HW_)
                          : (mask_labels + ((size_t)b * T_ + (x - Q_)) * HW_);
  const float4* s4 = (const float4*)src;
#pragma unroll
  for (int c = 0; c < 6; ++c) {
    int i = c * SBLK + tid;
    float4 v = s4[i];
    ushort4 u;
    u.x = f2bf(v.x); u.y = f2bf(v.y); u.z = f2bf(v.z); u.w = f2bf(v.w);
    *(ushort4*)&img[4 * i] = u;
  }
  if (tid < HW4_ - 6 * SBLK) {  // 6400 - 6144 = 256
    int i = 6 * SBLK + tid;
    float4 v = s4[i];
    ushort4 u;
    u.x = f2bf(v.x); u.y = f2bf(v.y); u.z = f2bf(v.z); u.w = f2bf(v.w);
    *(ushort4*)&img[4 * i] = u;
  }
  __syncthreads();

  const uint4* sp = sPack + (size_t)b * P_;

  if (isPm) {
    unsigned short* dst = pmh + ((size_t)b * QP_ + x) * P_;
    unsigned* dst32 = (unsigned*)dst;
    float ssp = 0.f, ssg = 0.f;
#pragma unroll
    for (int bat = 0; bat < 2; ++bat) {
      uint4 pk[6];
#pragma unroll
      for (int cc = 0; cc < 3; ++cc) {
        int p = (bat * 3 + cc) * 2048 + 2 * tid;
        pk[2 * cc] = sp[p];
        pk[2 * cc + 1] = sp[p + 1];
      }
      float v[6];
#pragma unroll
      for (int j = 0; j < 6; ++j) v[j] = lds4(img, pk[j]);
#pragma unroll
      for (int cc = 0; cc < 3; ++cc) {
        unsigned pr = 0;
#pragma unroll
        for (int k = 0; k < 2; ++k) {
          float pm = v[2 * cc + k];
          float e = __expf(-fabsf(pm));
          float r = __builtin_amdgcn_rcpf(1.f + e);
          float sp_ = fmaxf(pm, 0.f) - __logf(r);
          float sg = (pm >= 0.f) ? r : e * r;
          ssp += sp_;
          ssg += sg;
          pr |= ((unsigned)f2bf(pm)) << (16 * k);
        }
        dst32[(bat * 3 + cc) * 1024 + tid] = pr;
      }
    }
    if (tid < TAILP) {
      int p = NCHUNK * 2048 + 2 * tid;
      uint4 a = sp[p], c = sp[p + 1];
      float v0 = lds4(img, a), v1 = lds4(img, c);
      unsigned pr = 0;
#pragma unroll
      for (int k = 0; k < 2; ++k) {
        float pm = (k == 0) ? v0 : v1;
        float e = __expf(-fabsf(pm));
        float r = __builtin_amdgcn_rcpf(1.f + e);
        float sp_ = fmaxf(pm, 0.f) - __logf(r);
        float sg = (pm >= 0.f) ? r : e * r;
        ssp += sp_;
        ssg += sg;
        pr |= ((unsigned)f2bf(pm)) << (16 * k);
      }
      dst32[(NCHUNK * 2048 + 2 * tid) >> 1] = pr;
    }
    ssp = waveSum(ssp);
    ssg = waveSum(ssg);
    int w = tid >> 6;
    if ((tid & 63) == 0) {
      red[w] = ssp;
      red[16 + w] = ssg;
    }
    __syncthreads();
    if (tid == 0) {
      float a = 0.f, bb = 0.f;
#pragma unroll
      for (int i = 0; i < 16; ++i) { a += red[i]; bb += red[16 + i]; }
      S_sp[b * Q_ + x] = a;
      S_sig[b * Q_ + x] = bb;
    }
  } else {
    const int t = x - Q_;
    unsigned short* dst = tmh + ((size_t)b * T_ + t) * P_;
    unsigned* dst32 = (unsigned*)dst;
    float stm = 0.f;
#pragma unroll
    for (int bat = 0; bat < 2; ++bat) {
      uint4 pk[6];
#pragma unroll
      for (int cc = 0; cc < 3; ++cc) {
        int p = (bat * 3 + cc) * 2048 + 2 * tid;
        pk[2 * cc] = sp[p];
        pk[2 * cc + 1] = sp[p + 1];
      }
      float v[6];
#pragma unroll
      for (int j = 0; j < 6; ++j) v[j] = lds4(img, pk[j]);
#pragma unroll
      for (int cc = 0; cc < 3; ++cc) {
        float v0 = v[2 * cc], v1 = v[2 * cc + 1];
        stm += v0 + v1;
        unsigned pr = (unsigned)f2bf(v0) | (((unsigned)f2bf(v1)) << 16);
        dst32[(bat * 3 + cc) * 1024 + tid] = pr;
      }
    }
    if (tid < TAILP) {
      int p = NCHUNK * 2048 + 2 * tid;
      uint4 a = sp[p], c = sp[p + 1];
      float v0 = lds4(img, a), v1 = lds4(img, c);
      stm += v0 + v1;
      unsigned pr = (unsigned)f2bf(v0) | (((unsigned)f2bf(v1)) << 16);
      dst32[(NCHUNK * 2048 + 2 * tid) >> 1] = pr;
    }
    stm = waveSum(stm);
    int w = tid >> 6;
    if ((tid & 63) == 0) red[w] = stm;
    __syncthreads();
    if (tid == 0) {
      float a = 0.f;
#pragma unroll
      for (int i = 0; i < 16; ++i) a += red[i];
      S_tm[b * T_ + t] = a;
    }
  }
}

// convert a pm bf16 A-frag to a sigmoid(pm) bf16 A-frag, elementwise
__device__ __forceinline__ short8 sig_frag(short8 a) {
  short8 out;
#pragma unroll
  for (int j = 0; j < 8; ++j) {
    float x = bf2f((unsigned short)a[j]);
    float e = __expf(-fabsf(x));
    float r = __builtin_amdgcn_rcpf(1.f + e);
    float sg = (x >= 0.f) ? r : e * r;
    out[j] = (short)f2bf(sg);
  }
  return out;
}

// ---------------- phase 3: K-split MFMA GEMM, atomic-free partials.
// Block (seg,b): 5 waves; wave w owns rows 32w..32w+31, both n-tiles,
// both matrices (sig computed in-register from pm frags).
__launch_bounds__(320) __global__
void gemm_kernel(const unsigned short* __restrict__ pmh,
                 const unsigned short* __restrict__ tmh,
                 float* __restrict__ accP) {
  const int b = blockIdx.y;
  const int seg = blockIdx.x;
  const int w = threadIdx.x >> 6;
  const int l = threadIdx.x & 63;
  const int quad = l >> 4;
  const int mrow = l & 15;

  const unsigned short* pmb = pmh + ((size_t)b * QP_ + w * 32) * P_;
  const unsigned short* tmb = tmh + (size_t)b * T_ * P_;

  floatx4 aL[2][2];  // [m-tile local][n-tile]
  floatx4 aS[2][2];
#pragma unroll
  for (int i = 0; i < 2; ++i)
#pragma unroll
    for (int j = 0; j < 2; ++j) {
      aL[i][j] = (floatx4){0.f, 0.f, 0.f, 0.f};
      aS[i][j] = (floatx4){0.f, 0.f, 0.f, 0.f};
    }

  const int kbase = seg * KSEG;
#pragma unroll
  for (int ki = 0; ki < KITER; ++ki) {
    const int k0 = kbase + ki * 32 + quad * 8;
    short8 a0 = *(const short8*)(pmb + (size_t)(0 * 16 + mrow) * P_ + k0);
    short8 a1 = *(const short8*)(pmb + (size_t)(1 * 16 + mrow) * P_ + k0);
    short8 b0 = *(const short8*)(tmb + (size_t)(0 * 16 + mrow) * P_ + k0);
    short8 b1 = *(const short8*)(tmb + (size_t)(1 * 16 + mrow) * P_ + k0);
    short8 s0 = sig_frag(a0);
    short8 s1 = sig_frag(a1);
    aL[0][0] = __builtin_amdgcn_mfma_f32_16x16x32_bf16(a0, b0, aL[0][0], 0, 0, 0);
    aL[0][1] = __builtin_amdgcn_mfma_f32_16x16x32_bf16(a0, b1, aL[0][1], 0, 0, 0);
    aL[1][0] = __builtin_amdgcn_mfma_f32_16x16x32_bf16(a1, b0, aL[1][0], 0, 0, 0);
    aL[1][1] = __builtin_amdgcn_mfma_f32_16x16x32_bf16(a1, b1, aL[1][1], 0, 0, 0);
    aS[0][0] = __builtin_amdgcn_mfma_f32_16x16x32_bf16(s0, b0, aS[0][0], 0, 0, 0);
    aS[0][1] = __builtin_amdgcn_mfma_f32_16x16x32_bf16(s0, b1, aS[0][1], 0, 0, 0);
    aS[1][0] = __builtin_amdgcn_mfma_f32_16x16x32_bf16(s1, b0, aS[1][0], 0, 0, 0);
    aS[1][1] = __builtin_amdgcn_mfma_f32_16x16x32_bf16(s1, b1, aS[1][1], 0, 0, 0);
  }

  // epilogue: plain stores. D layout: row(m)=quad*4+reg, col(n)=lane&15
  float* base = accP + (size_t)seg * DSTRIDE;
#pragma unroll
  for (int mtl = 0; mtl < 2; ++mtl)
#pragma unroll
    for (int nt = 0; nt < 2; ++nt)
#pragma unroll
      for (int r = 0; r < 4; ++r) {
        int q = w * 32 + mtl * 16 + quad * 4 + r;
        int t = nt * 16 + mrow;
        base[((size_t)(0 * B_ + b) * QP_ + q) * T_ + t] = aL[mtl][nt][r];
        base[((size_t)(1 * B_ + b) * QP_ + q) * T_ + t] = aS[mtl][nt][r];
      }
}

// ---------------- phase 4: finalize (reduce fused). one wave per (b,q).
// Lane l sums accP over segments for mat=(l>>5), t=(l&31); shfl pairs them.
__launch_bounds__(64) __global__
void final_kernel(const float* __restrict__ class_q,
                  const int* __restrict__ labels,
                  const float* __restrict__ accP,
                  const float* __restrict__ S_sp,
                  const float* __restrict__ S_sig,
                  const float* __restrict__ S_tm,
                  float* __restrict__ out) {
  const int bq = blockIdx.x;
  const int b = bq / Q_;
  const int q = bq % Q_;
  const int l = threadIdx.x;
  const float* cl = class_q + (size_t)bq * C_;

  // segment reduction: lane l -> matrix (l>>5), column (l&31)
  const int mat = l >> 5;
  const int t = l & 31;
  const float* ap = accP + ((size_t)(mat * B_ + b) * QP_ + q) * T_ + t;
  float s = 0.f;
#pragma unroll
  for (int seg = 0; seg < SEG_; ++seg) s += ap[(size_t)seg * DSTRIDE];
  float sOther = __shfl_xor(s, 32, 64);   // lane<32: Dsig from lane+32

  float v = -INFINITY;
  for (int c = l; c < C_; c += 64) v = fmaxf(v, cl[c]);
  float m = waveMax(v);
  float e = 0.f;
  for (int c = l; c < C_; c += 64) e += __expf(cl[c] - m);
  float den = waveSum(e);

  if (l < T_) {
    int lbl = labels[b * T_ + t];
    float prob = __expf(cl[lbl] - m) / den;
    float Dlin = s;
    float Dsig = sOther;
    float cmask = (S_sp[bq] - Dlin) * (1.f / (float)P_);
    float dice = 1.f - (2.f * Dsig + 1.f) / (S_sig[bq] + S_tm[b * T_ + t] + 1.f);
    out[(size_t)bq * T_ + t] = 5.f * cmask + 5.f * dice - prob;
  }
}

extern "C" void kernel_launch(void* const* d_in, const int* in_sizes, int n_in,
                              void* d_out, int out_size, void* d_ws,
                              size_t ws_size, hipStream_t stream) {
  const float* masks_q = (const float*)d_in[0];      // [B,Q,H,W]
  const float* class_q = (const float*)d_in[1];      // [B,Q,C]
  const float* mask_labels = (const float*)d_in[2];  // [B,T,H,W]
  const int* class_labels = (const int*)d_in[3];     // [B,T]
  const float* coords = (const float*)d_in[4];       // [B,P,2]
  float* out = (float*)d_out;

  // ws layout (accD slot retained for layout stability; unused now)
  float* accD = (float*)d_ws;                         // [2][B][QP_][T_] (unused)
  float* accP = accD + DSTRIDE;                       // [SEG_][2][B][QP_][T_]
  uint4* sPack = (uint4*)(accP + (size_t)SEG_ * DSTRIDE);  // [B*P] (16B aligned)
  float* S_sp = (float*)(sPack + (size_t)B_ * P_);    // [B*Q]
  float* S_sig = S_sp + B_ * Q_;                      // [B*Q]
  float* S_tm = S_sig + B_ * Q_;                      // [B*T]
  unsigned short* pmh = (unsigned short*)(S_tm + B_ * T_);  // [B][QP_][P]
  unsigned short* tmh = pmh + (size_t)B_ * QP_ * P_;        // [B][T][P]

  samp_kernel<<<(B_ * P_) / 256, 256, 0, stream>>>(coords, sPack);
  sample_kernel<<<dim3(Q_ + T_, B_), SBLK, 0, stream>>>(
      masks_q, mask_labels, sPack, pmh, tmh, S_sp, S_sig, S_tm);
  gemm_kernel<<<dim3(SEG_, B_), 320, 0, stream>>>(pmh, tmh, accP);
  final_kernel<<<B_ * Q_, 64, 0, stream>>>(class_q, class_labels, accP, S_sp,
                                           S_sig, S_tm, out);
}